// Round 5
// baseline (4079.042 us; speedup 1.0000x reference)
//
#include <hip/hip_runtime.h>
#include <stdint.h>

#define AGENT __HIP_MEMORY_SCOPE_AGENT
typedef unsigned long long u64;

// x[64][256][256] -> xT[t][k][b]  (k-major, batch-minor: consumers read
// x[k][b..b+3] as float4). Reads are per-lane rows (uncoalesced, one-shot
// 16MB kernel); writes coalesce per k (256B/instr).
__global__ __launch_bounds__(256) void xpose_in(const float* __restrict__ x,
                                                float* __restrict__ xT) {
  const int t = blockIdx.x;
  const int b = threadIdx.x & 63;
  const int w = threadIdx.x >> 6;
  const float* xr = x + ((size_t)b * 256 + t) * 256;
  float* o = xT + (size_t)t * 256 * 64;
  for (int kq = w * 16; kq < w * 16 + 16; ++kq) {
    float4 v = *(const float4*)(xr + kq * 4);
    o[(size_t)(kq * 4 + 0) * 64 + b] = v.x;
    o[(size_t)(kq * 4 + 1) * 64 + b] = v.y;
    o[(size_t)(kq * 4 + 2) * 64 + b] = v.z;
    o[(size_t)(kq * 4 + 3) * 64 + b] = v.w;
  }
}

// Pack [W;U] ([KT][4H]) into quad-major per-WG blocks:
//   out[((wg*KTq + q)*16 + c)*4 + j] = WU[k=4q+j][col = g*H + wg*4 + jl],
// c = g*4 + jl. One b128 = one c-row x 4 k's. Worker stages the whole WG
// block (48KB max) into LDS once; reads are 4-unique-address b128
// (lane cq in {0..3}) -> 2-way bank conflict = free (m136).
__global__ __launch_bounds__(256) void pack_wu(const float* __restrict__ W,
                                               const float* __restrict__ U,
                                               float* __restrict__ out,
                                               int DIN, int H) {
  __shared__ float tile[64][65];
  const int KT = DIN + H;
  const int KTq = KT >> 2;
  const int c0 = blockIdx.x * 64;  // column tile base (4H dim)
  const int k0 = blockIdx.y * 64;  // k tile base
  const int tx = threadIdx.x & 63;
  const int ty = threadIdx.x >> 6;
  for (int r = ty; r < 64; r += 4) {
    const int k = k0 + r;
    tile[r][tx] = (k < DIN) ? W[(size_t)k * (4 * H) + c0 + tx]
                            : U[(size_t)(k - DIN) * (4 * H) + c0 + tx];
  }
  __syncthreads();
  // tile[a][b] = WU[k0+a][c0+b]; thread (r,tx) emits (col=c0+r, k=k0+tx)
  for (int r = ty; r < 64; r += 4) {
    const int cg = c0 + r;
    const int g = cg / H;
    const int col = cg - g * H;
    const int wg = col >> 2;
    const int jl = col & 3;
    const int c = (g << 2) | jl;
    const int k = k0 + tx;
    const int q = k >> 2;
    const int j = k & 3;
    out[(((size_t)wg * KTq + q) * 16 + c) * 4 + j] = tile[tx][r];
  }
}

#define SB __builtin_amdgcn_sched_barrier(0)
// Round-1 lesson: macro params must NOT be named x/y/z/w (member capture).
// x0_..x3_ are the quad's 4 k-vectors (component M_ = batch j), W_ is one
// c-row's 4 k-weights (components = k).
#define FMA_K4(A_, W_, M_)                                            \
  A_ = fmaf((W_).x, x0_.M_, A_); A_ = fmaf((W_).y, x1_.M_, A_);       \
  A_ = fmaf((W_).z, x2_.M_, A_); A_ = fmaf((W_).w, x3_.M_, A_);
#define FMA_ROW16(W_, O_)      \
  FMA_K4(acc[(O_) + 0], W_, x) \
  FMA_K4(acc[(O_) + 1], W_, y) \
  FMA_K4(acc[(O_) + 2], W_, z) \
  FMA_K4(acc[(O_) + 3], W_, w)

// Buffer fills for one 2-quad step S_: 8 global dwordx4 (x) / 8 ds_read_b128
// (w). Buffer layout: [hq*4 + j] = quad (2*S_+hq), k-component/c-row j.
#define PFX(XB_, S_)                                                      \
  {                                                                       \
    _Pragma("unroll") for (int j_ = 0; j_ < 8; ++j_)                      \
        XB_[j_] =                                                         \
        src4[(size_t)((S_)*2 + (j_ >> 2)) * 64 + (j_ & 3) * 16 + bq];     \
  }
#define PFW(WB_, S_)                                                      \
  {                                                                       \
    _Pragma("unroll") for (int j_ = 0; j_ < 8; ++j_)                      \
        WB_[j_] = wl4[((S_)*2 + (j_ >> 2)) * 16 + cq4 + (j_ & 3)];        \
  }
// 128 FMAs consuming one step's buffers (2 quads x 4 c-rows x 16).
#define FMA2Q(XB_, WB_)                                                   \
  {                                                                       \
    {                                                                     \
      const float4 x0_ = XB_[0], x1_ = XB_[1], x2_ = XB_[2], x3_ = XB_[3];\
      FMA_ROW16(WB_[0], 0) FMA_ROW16(WB_[1], 4)                           \
      FMA_ROW16(WB_[2], 8) FMA_ROW16(WB_[3], 12)                          \
    }                                                                     \
    {                                                                     \
      const float4 x0_ = XB_[4], x1_ = XB_[5], x2_ = XB_[6], x3_ = XB_[7];\
      FMA_ROW16(WB_[4], 0) FMA_ROW16(WB_[5], 4)                           \
      FMA_ROW16(WB_[6], 8) FMA_ROW16(WB_[7], 12)                          \
    }                                                                     \
  }

// Register-tile accumulate, software-pipelined (round-4 post-mortem: the
// [loads][FMA] SB [loads][FMA] structure has ZERO lookahead — in-order
// waves expose the full L2/LLC load latency (250-600cyc) every 4-quad
// group; VALUBusy stuck at 35%). Now: 2-quad steps, double-buffered x
// (VMEM) and w (LDS); step s+1's 16 loads issue BEFORE step s's 128 FMAs
// (~320cyc of cover). Rolled outer loop (2 steps/iter) keeps code ~300
// instrs (no I$ thrash) and regs ~160 (no spill at 2 waves/SIMD).
// lane = (cq = lane>>4, bq = lane&15); acc[i][j] = z(c=cq*4+i, b=bq*4+j).
// Summation order unchanged from round 4 (same absmax).
template <int QW>
__device__ __forceinline__ void accum_cb(const float4* __restrict__ src4,
                                         const float4* __restrict__ wl4,
                                         int bq, int cq4, float acc[16]) {
  static_assert(QW % 4 == 0, "pipeline assumes 4|QW");
  constexpr int NS = QW / 2;  // 2-quad steps, NS even
  float4 X0[8], X1[8], W0[8], W1[8];
  PFX(X0, 0) PFW(W0, 0)
#pragma unroll 1
  for (int s = 0; s < NS; s += 2) {
    PFX(X1, s + 1) PFW(W1, s + 1)
    FMA2Q(X0, W0)
    SB;
    if (s + 2 < NS) { PFX(X0, s + 2) PFW(W0, s + 2) }
    FMA2Q(X1, W1)
    SB;
  }
}

// Dedicated per-layer aggregator: one wave gathers this layer's NWG per-WG
// flags for tick t, then publishes a single monotonic epoch word (= ticks
// completed). Consumers poll ONLY the epoch word (1 lane, 1 line).
template <int NWG>
__device__ __forceinline__ void agg_body(unsigned* __restrict__ flg,
                                         unsigned* __restrict__ ep) {
  const int tid = threadIdx.x;
  if (tid >= 64) return;  // single wave
  for (int t = 0; t < 256; ++t) {
    unsigned* base = flg + (size_t)t * NWG;
    if (NWG <= 64) {
      if (tid < NWG) {
        while (__hip_atomic_load(base + tid, __ATOMIC_RELAXED, AGENT) == 0u)
          __builtin_amdgcn_s_sleep(1);
      }
    } else {
      while (__hip_atomic_load(base + tid, __ATOMIC_RELAXED, AGENT) == 0u)
        __builtin_amdgcn_s_sleep(1);
      while (__hip_atomic_load(base + 64 + tid, __ATOMIC_RELAXED, AGENT) == 0u)
        __builtin_amdgcn_s_sleep(1);
    }
    asm volatile("s_waitcnt vmcnt(0)" ::: "memory");
    if (tid == 0)
      __hip_atomic_store(ep, (unsigned)(t + 1), __ATOMIC_RELAXED, AGENT);
  }
}

// One pipelined LSTM layer. 256-thread WG owns hidden quad wg (4 units);
// all 16 weight rows staged ONCE into LDS (48KB max, quad-major). Waves
// split K 4-ways (wave = kb); lane = (cq,bq) register tile. Epilogue:
// wave jl owns unit jl. h stored [t][unit][b] (b-minor). Poll order
// (round-5): XCOH layers poll prevE first, do the x-projection, THEN poll
// selfE — x-work hides own-layer peer straggle (the binding barrier),
// mirroring L0's static-x overlap. Sync: per-WG flags -> aggregator ->
// epoch word; workers poll one word with one lane.
template <int DIN, int H, int NWG, bool FIN, bool XCOH>
__device__ __forceinline__ void layer_body(
    int wg, int tid, const float* __restrict__ xin, float* __restrict__ hseq,
    const float* __restrict__ wP, const float* __restrict__ bias,
    float* __restrict__ dout, unsigned* __restrict__ selfF,
    unsigned* __restrict__ selfE, unsigned* __restrict__ prevE,
    float* __restrict__ wL, float (*sZ)[16][64], float* sH) {
  constexpr int KT = DIN + H;
  constexpr int KTq = KT / 4;
  constexpr int QX = DIN / 16;  // x-quads per wave (K-split 4)
  constexpr int QH = H / 16;    // h-quads per wave
  constexpr int T = 256;
  static_assert(QX % 4 == 0 && QH % 4 == 0, "pipeline assumes 4|QW");

  const int lane = tid & 63;
  const int wv = tid >> 6;          // K-split slice kb; also unit jl in epilogue
  const int bq = lane & 15;         // batch quad (4 batches)
  const int cq4 = (lane >> 4) * 4;  // first of this lane's 4 c-rows

  // ---- stage the WG's full weight block into LDS (once), layout [q][c] ----
  {
    float4* wl = (float4*)wL;
    const float4* wp = (const float4*)wP + (size_t)wg * KTq * 16;
    for (int i = tid; i < KTq * 16; i += 256) wl[i] = wp[i];
  }
  const float4* wl4x = (const float4*)wL + (size_t)wv * QX * 16;
  const float4* wl4h = (const float4*)wL + ((size_t)(DIN / 4) + wv * QH) * 16;

  float bz[4];
#pragma unroll
  for (int g = 0; g < 4; ++g) bz[g] = bias[g * H + wg * 4 + wv];
  float cst = 0.f;
  __syncthreads();

  for (int t = 0; t < T; ++t) {
    float acc[16];
#pragma unroll
    for (int c = 0; c < 16; ++c) acc[c] = 0.f;

    if (!XCOH) {
      // layer 0: x static — overlap input projection with waiting for peers
      accum_cb<QX>((const float4*)(xin + (size_t)t * DIN * 64) +
                       (size_t)wv * QX * 64,
                   wl4x, bq, cq4, acc);
      if (t > 0 && tid == 0) {
        while (__hip_atomic_load(selfE, __ATOMIC_RELAXED, AGENT) < (unsigned)t)
          __builtin_amdgcn_s_sleep(2);
      }
      __syncthreads();
      asm volatile("" ::: "memory");
    } else {
      // wait only for prev layer (usually already satisfied: producers run
      // ahead), project x, THEN barrier on own layer (the binding wait).
      if (tid == 64) {
        while (__hip_atomic_load(prevE, __ATOMIC_RELAXED, AGENT) <
               (unsigned)(t + 1))
          __builtin_amdgcn_s_sleep(2);
      }
      __syncthreads();
      asm volatile("" ::: "memory");  // no hoist of x loads above poll
      accum_cb<QX>((const float4*)(xin + (size_t)t * DIN * 64) +
                       (size_t)wv * QX * 64,
                   wl4x, bq, cq4, acc);
      if (t > 0 && tid == 0) {
        while (__hip_atomic_load(selfE, __ATOMIC_RELAXED, AGENT) < (unsigned)t)
          __builtin_amdgcn_s_sleep(2);
      }
      __syncthreads();
      asm volatile("" ::: "memory");  // no hoist of h loads above poll
    }

    if (t > 0) {
      accum_cb<QH>((const float4*)(hseq + (size_t)(t - 1) * H * 64) +
                       (size_t)wv * QH * 64,
                   wl4h, bq, cq4, acc);
    }

    // 4-way K-split reduction: thread (kb=wv, cq, bq) -> sZ[kb][c][b]
#pragma unroll
    for (int i = 0; i < 4; ++i) {
      *(float4*)&sZ[wv][cq4 + i][bq * 4] = make_float4(
          acc[i * 4 + 0], acc[i * 4 + 1], acc[i * 4 + 2], acc[i * 4 + 3]);
    }
    __syncthreads();

    float z[4];
#pragma unroll
    for (int g = 0; g < 4; ++g) {
      z[g] = bz[g];
#pragma unroll
      for (int k = 0; k < 4; ++k) z[g] += sZ[k][g * 4 + wv][lane];
    }
    const float ig = 1.f / (1.f + __expf(-z[0]));
    const float fg = 1.f / (1.f + __expf(-z[1]));
    const float gg = FIN ? tanhf(z[2]) : fmaxf(z[2], 0.f);
    const float og = 1.f / (1.f + __expf(-z[3]));
    cst = fg * cst + ig * gg;
    const float ca = FIN ? tanhf(cst) : fmaxf(cst, 0.f);
    const float h = og * ca;
    sH[lane * 4 + wv] = h;  // [b][jl]
    if (FIN && t == T - 1) dout[(size_t)lane * H + wg * 4 + wv] = h;
    __syncthreads();

    // wave 0 publishes the WG's 4 unit-rows in [t][unit][b] layout
    // (agent write-through, coalesced 256B per row), then signals.
    if (wv == 0) {
      float* hw = hseq + (size_t)t * H * 64 + (size_t)(wg * 4) * 64 + lane;
#pragma unroll
      for (int jl = 0; jl < 4; ++jl) {
        __hip_atomic_store(hw + jl * 64, sH[lane * 4 + jl], __ATOMIC_RELAXED,
                           AGENT);
      }
      asm volatile("s_waitcnt vmcnt(0)" ::: "memory");
      if (tid == 0)
        __hip_atomic_store(&selfF[t * NWG + wg], 1u, __ATOMIC_RELAXED, AGENT);
    }
  }
}

__global__ __launch_bounds__(256, 2) void lstm_fused(
    const float* __restrict__ xT, float* __restrict__ h0,
    float* __restrict__ h1, float* __restrict__ h2, float* __restrict__ h3,
    float* __restrict__ h4, float* __restrict__ h5,
    const float* __restrict__ wuT0, const float* __restrict__ wuT1,
    const float* __restrict__ wuT2, const float* __restrict__ wuT3,
    const float* __restrict__ wuT4, const float* __restrict__ wuT5,
    const float* __restrict__ b0, const float* __restrict__ b1,
    const float* __restrict__ b2, const float* __restrict__ b3,
    const float* __restrict__ b4, const float* __restrict__ b5,
    float* __restrict__ dout, unsigned* __restrict__ f0,
    unsigned* __restrict__ f1, unsigned* __restrict__ f2,
    unsigned* __restrict__ f3, unsigned* __restrict__ f4,
    unsigned* __restrict__ f5, unsigned* __restrict__ eps) {
  __shared__ alignas(16) float wLDS[16 * 768];  // 48 KB (max KTq=192)
  __shared__ alignas(16) float sZ[4][16][64];   // 16 KB
  __shared__ alignas(16) float sH[256];         // 1 KB
  const int b = blockIdx.x;
  const int tid = threadIdx.x;
  // heavy layers (L0, L4) first so they land one-per-CU; aggregators last
  if (b < 128) {
    layer_body<256, 512, 128, false, false>(b, tid, xT, h0, wuT0, b0, nullptr,
                                            f0, eps + 0, nullptr, wLDS, sZ, sH);
  } else if (b < 256) {
    layer_body<256, 512, 128, false, true>(b - 128, tid, h3, h4, wuT4, b4,
                                           nullptr, f4, eps + 4, eps + 3, wLDS,
                                           sZ, sH);
  } else if (b < 320) {
    layer_body<512, 256, 64, false, true>(b - 256, tid, h0, h1, wuT1, b1,
                                          nullptr, f1, eps + 1, eps + 0, wLDS,
                                          sZ, sH);
  } else if (b < 384) {
    layer_body<64, 256, 64, false, true>(b - 320, tid, h2, h3, wuT3, b3,
                                         nullptr, f3, eps + 3, eps + 2, wLDS,
                                         sZ, sH);
  } else if (b < 448) {
    layer_body<512, 256, 64, true, true>(b - 384, tid, h4, h5, wuT5, b5, dout,
                                         f5, eps + 5, eps + 4, wLDS, sZ, sH);
  } else if (b < 464) {
    layer_body<256, 64, 16, false, true>(b - 448, tid, h1, h2, wuT2, b2,
                                         nullptr, f2, eps + 2, eps + 1, wLDS,
                                         sZ, sH);
  } else {
    const int l = b - 464;
    if (l == 0) agg_body<128>(f0, eps + 0);
    else if (l == 1) agg_body<64>(f1, eps + 1);
    else if (l == 2) agg_body<16>(f2, eps + 2);
    else if (l == 3) agg_body<64>(f3, eps + 3);
    else if (l == 4) agg_body<128>(f4, eps + 4);
    else agg_body<64>(f5, eps + 5);
  }
}

extern "C" void kernel_launch(void* const* d_in, const int* in_sizes, int n_in,
                              void* d_out, int out_size, void* d_ws,
                              size_t ws_size, hipStream_t stream) {
  (void)in_sizes; (void)n_in; (void)out_size; (void)ws_size;
  const float* x = (const float*)d_in[0];
  const float* W[6];
  const float* U[6];
  const float* B[6];
  for (int l = 0; l < 6; ++l) {
    W[l] = (const float*)d_in[1 + 3 * l];
    U[l] = (const float*)d_in[2 + 3 * l];
    B[l] = (const float*)d_in[3 + 3 * l];
  }
  char* ws = (char*)d_ws;
  // flags: [T][NWG] per layer; NWG = 128,64,16,64,128,64; then 6 epochs
  unsigned* f0 = (unsigned*)ws;
  unsigned* f1 = f0 + 128 * 256;
  unsigned* f2 = f1 + 64 * 256;
  unsigned* f3 = f2 + 16 * 256;
  unsigned* f4 = f3 + 64 * 256;
  unsigned* f5 = f4 + 128 * 256;
  unsigned* eps = f0 + 464 * 256;
  float* wuT0 = (float*)(ws + (1u << 20));
  float* wuT1 = wuT0 + (size_t)2048 * 768;
  float* wuT2 = wuT1 + (size_t)1024 * 768;
  float* wuT3 = wuT2 + (size_t)256 * 320;
  float* wuT4 = wuT3 + (size_t)1024 * 320;
  float* wuT5 = wuT4 + (size_t)2048 * 768;
  float* xT = (float*)(ws + (22u << 20));   // 16 MB
  float* h0 = (float*)(ws + (38u << 20));   // 32 MB
  float* h1 = (float*)(ws + (70u << 20));   // 16 MB
  float* h2 = (float*)(ws + (86u << 20));   // 4 MB
  float* h3 = (float*)(ws + (90u << 20));   // 16 MB
  float* h4 = (float*)(ws + (106u << 20));  // 32 MB
  float* h5 = (float*)(ws + (138u << 20));  // 16 MB (full T, no ring)

  hipMemsetAsync(f0, 0, (464 * 256 + 8) * sizeof(unsigned), stream);
  xpose_in<<<256, 256, 0, stream>>>(x, xT);
  pack_wu<<<dim3(32, 12), 256, 0, stream>>>(W[0], U[0], wuT0, 256, 512);
  pack_wu<<<dim3(16, 12), 256, 0, stream>>>(W[1], U[1], wuT1, 512, 256);
  pack_wu<<<dim3(4, 5), 256, 0, stream>>>(W[2], U[2], wuT2, 256, 64);
  pack_wu<<<dim3(16, 5), 256, 0, stream>>>(W[3], U[3], wuT3, 64, 256);
  pack_wu<<<dim3(32, 12), 256, 0, stream>>>(W[4], U[4], wuT4, 256, 512);
  pack_wu<<<dim3(16, 12), 256, 0, stream>>>(W[5], U[5], wuT5, 512, 256);

  lstm_fused<<<470, 256, 0, stream>>>(xT, h0, h1, h2, h3, h4, h5, wuT0, wuT1,
                                      wuT2, wuT3, wuT4, wuT5, B[0], B[1], B[2],
                                      B[3], B[4], B[5], (float*)d_out, f0, f1,
                                      f2, f3, f4, f5, eps);
}